// Round 14
// baseline (153.607 us; speedup 1.0000x reference)
//
#include <hip/hip_runtime.h>

#define CC 512
#define NPIX 4096
#define NB 2
#define NG 32
#define GSIZE 16
#define EPS 1e-6f

typedef unsigned short u16;
typedef __bf16 bf16x8 __attribute__((ext_vector_type(8)));
typedef float f32x4 __attribute__((ext_vector_type(4)));

__device__ __forceinline__ float bf2f(u16 u) {
  union { unsigned int i; float f; } c; c.i = ((unsigned int)u) << 16; return c.f;
}
__device__ __forceinline__ u16 f2bf(float f) {
  union { float f; unsigned int i; } c; c.f = f;
  unsigned int u = c.i;
  return (u16)((u + 0x7fffu + ((u >> 16) & 1u)) >> 16);
}

// ---- fp32 -> bf16 conversion for 4 weight matrices in one launch ----
__global__ __launch_bounds__(256) void f2bf4x4_kernel(
    const float* __restrict__ s0, const float* __restrict__ s1,
    const float* __restrict__ s2, const float* __restrict__ s3,
    u16* __restrict__ d0, u16* __restrict__ d1,
    u16* __restrict__ d2, u16* __restrict__ d3) {
  const float* s; u16* d;
  switch (blockIdx.y) {
    case 0: s = s0; d = d0; break;
    case 1: s = s1; d = d1; break;
    case 2: s = s2; d = d2; break;
    default: s = s3; d = d3; break;
  }
  int i = blockIdx.x * 256 + threadIdx.x;
  float4 v = ((const float4*)s)[i];
  uint2 pk;
  pk.x = (unsigned)f2bf(v.x) | ((unsigned)f2bf(v.y) << 16);
  pk.y = (unsigned)f2bf(v.z) | ((unsigned)f2bf(v.w) << 16);
  ((uint2*)d)[i] = pk;
}

// ---- concat two 512-float bias vectors ----
__global__ __launch_bounds__(256) void concat2_kernel(const float* __restrict__ a,
                                                      const float* __restrict__ b,
                                                      float* __restrict__ o) {
  int i = blockIdx.x * 256 + threadIdx.x;  // 0..1023
  o[i] = (i < CC) ? a[i] : b[i - CC];
}

// ---- GroupNorm stats, stage 1: 8 partial (sum,sumsq) per (b,g) ----
__global__ __launch_bounds__(256) void gn_stats_part(const float* __restrict__ x,
                                                     float* __restrict__ part) {
  int bg = blockIdx.x >> 3;   // 0..63
  int ch = blockIdx.x & 7;    // 0..7
  const int CHUNK4 = GSIZE * NPIX / 8 / 4;  // 2048 float4
  const float4* p = (const float4*)(x + (long)bg * (GSIZE * NPIX)) + ch * CHUNK4;
  float s = 0.f, ss = 0.f;
  for (int i = threadIdx.x; i < CHUNK4; i += 256) {
    float4 v = p[i];
    s  += v.x + v.y + v.z + v.w;
    ss += v.x * v.x + v.y * v.y + v.z * v.z + v.w * v.w;
  }
  for (int off = 32; off; off >>= 1) { s += __shfl_xor(s, off); ss += __shfl_xor(ss, off); }
  __shared__ float rs[4], rss[4];
  int wid = threadIdx.x >> 6;
  if ((threadIdx.x & 63) == 0) { rs[wid] = s; rss[wid] = ss; }
  __syncthreads();
  if (threadIdx.x == 0) {
    part[blockIdx.x * 2]     = rs[0] + rs[1] + rs[2] + rs[3];
    part[blockIdx.x * 2 + 1] = rss[0] + rss[1] + rss[2] + rss[3];
  }
}

// ---- GroupNorm stats, stage 2: finalize mean/rstd (64 threads) ----
__global__ __launch_bounds__(64) void gn_stats_fin(const float* __restrict__ part,
                                                   float* __restrict__ stats) {
  int bg = threadIdx.x;  // 0..63
  float s = 0.f, ss = 0.f;
  #pragma unroll
  for (int c = 0; c < 8; ++c) {
    s  += part[(bg * 8 + c) * 2];
    ss += part[(bg * 8 + c) * 2 + 1];
  }
  float mean = s / (float)(GSIZE * NPIX);
  float var = ss / (float)(GSIZE * NPIX) - mean * mean;
  stats[bg * 2] = mean;
  stats[bg * 2 + 1] = rsqrtf(var + EPS);
}

// ---- GN apply + transpose: x[b][c][n] -> hn[b][n][c] (bf16) ----
__global__ __launch_bounds__(256) void gn_apply_kernel(const float* __restrict__ x,
                                                       const float* __restrict__ stats,
                                                       const float* __restrict__ gw,
                                                       const float* __restrict__ gb,
                                                       u16* __restrict__ hn) {
  int n0 = blockIdx.x * 64, c0 = blockIdx.y * 64, b = blockIdx.z;
  __shared__ float tile[64][65];
  int t = threadIdx.x;
  int nj = t & 63, cw = t >> 6;
  #pragma unroll
  for (int r = 0; r < 16; ++r) {
    int ci = cw * 16 + r;
    int c = c0 + ci;
    float mean = stats[(b * NG + (c >> 4)) * 2];
    float rstd = stats[(b * NG + (c >> 4)) * 2 + 1];
    float v = x[((long)b * CC + c) * NPIX + n0 + nj];
    tile[ci][nj] = (v - mean) * rstd * gw[c] + gb[c];
  }
  __syncthreads();
  #pragma unroll
  for (int r = 0; r < 16; ++r) {
    int nn = cw * 16 + r;
    hn[((long)b * NPIX + n0 + nn) * CC + c0 + nj] = f2bf(tile[nj][nn]);
  }
}

// ---- reduce 16 per-bx partial rowsums into L[bz][row] ----
__global__ __launch_bounds__(256) void lred_kernel(const float* __restrict__ Lp,
                                                   float* __restrict__ L) {
  int i = blockIdx.x * 256 + threadIdx.x;  // bz*NPIX + row
  int bz = i / NPIX, row = i % NPIX;
  float s = 0.f;
  #pragma unroll
  for (int b = 0; b < 16; ++b) s += Lp[((long)bz * 16 + b) * NPIX + row];
  L[i] = s;
}

// ---- 128x128 NT GEMM (2-phase counted-vmcnt) ----
#define BM 128
#define BN 128
#define BKT 64
#define BUFSZ 8192  // u16 per half-buffer (one 128x64 operand tile)

template<int OUTF32, int BIASMODE, int RESID, int EPI>
__global__ __launch_bounds__(256) void gemm_nt(
    const u16* __restrict__ A, int lda, long aBatch,
    const u16* __restrict__ B, int ldb, long bBatch,
    void* __restrict__ C, int ldc, long cBatch,
    const float* __restrict__ bias,
    const float* __restrict__ resid, long rBatch,
    float* __restrict__ L, int lOff,
    int K, float scale) {
  __shared__ u16 SH[2 * 2 * BUFSZ];
  const int t = threadIdx.x;

  int nwgx = gridDim.x, nwgy = gridDim.y;
  int flat = blockIdx.x + nwgx * (blockIdx.y + nwgy * blockIdx.z);
  int nwg = nwgx * nwgy * gridDim.z;
  int newflat = (flat % 8) * (nwg / 8) + flat / 8;
  const int bx = newflat % nwgx;
  int tmpf = newflat / nwgx;
  const int by = tmpf % nwgy;
  const int bz = tmpf / nwgy;

  const int m0 = by * BM;
  const int n0 = bx * BN;
  const u16* Ab = A + (long)bz * aBatch;
  const u16* Bb = B + (long)bz * bBatch;

  const int lane = t & 63;
  const int wid = t >> 6;
  const int wr = (wid >> 1) * 64;
  const int wc = (wid & 1) * 64;
  const int r16 = lane & 15;
  const int q = lane >> 4;

  const int sRow = wid * 8 + (lane >> 3);              // + p*32
  const int sCol = (((lane & 7) ^ (lane >> 3)) * 8);   // swizzled global col (u16)

  f32x4 acc[4][4] = {};
  const int rsw = r16 & 7;  // read-side XOR key

  const int nt = K / BKT;

  auto stage = [&](int c, int k0) {
    u16* aDst = SH + c * 2 * BUFSZ + wid * 512;
    u16* bDst = SH + c * 2 * BUFSZ + BUFSZ + wid * 512;
    #pragma unroll
    for (int p = 0; p < 4; ++p) {
      __builtin_amdgcn_global_load_lds(
          (const __attribute__((address_space(1))) unsigned int*)(Ab + (long)(m0 + p * 32 + sRow) * lda + k0 + sCol),
          (__attribute__((address_space(3))) unsigned int*)(aDst + p * 2048),
          16, 0, 0);
      __builtin_amdgcn_global_load_lds(
          (const __attribute__((address_space(1))) unsigned int*)(Bb + (long)(n0 + p * 32 + sRow) * ldb + k0 + sCol),
          (__attribute__((address_space(3))) unsigned int*)(bDst + p * 2048),
          16, 0, 0);
    }
  };

  stage(0, 0);

  for (int tt = 0; tt < nt; ++tt) {
    const int pre = tt + 1;
    if (pre < nt) {
      stage(pre & 1, pre * BKT);
      asm volatile("s_waitcnt vmcnt(8)" ::: "memory");
    } else {
      asm volatile("s_waitcnt vmcnt(0)" ::: "memory");
    }
    __builtin_amdgcn_s_barrier();
    __builtin_amdgcn_sched_barrier(0);

    const u16* As_b = SH + (tt & 1) * 2 * BUFSZ;
    const u16* Bs_b = As_b + BUFSZ;
    #pragma unroll
    for (int kk = 0; kk < BKT; kk += 32) {
      bf16x8 af[4], bfr[4];
      const int c0q = (kk >> 3) + q;
      const int colSw = (c0q ^ rsw) * 8;
      #pragma unroll
      for (int i = 0; i < 4; ++i) {
        af[i]  = *(const bf16x8*)&As_b[(wr + i * 16 + r16) * BKT + colSw];
        bfr[i] = *(const bf16x8*)&Bs_b[(wc + i * 16 + r16) * BKT + colSw];
      }
      #pragma unroll
      for (int i = 0; i < 4; ++i)
        #pragma unroll
        for (int j = 0; j < 4; ++j)
          acc[i][j] = __builtin_amdgcn_mfma_f32_16x16x32_bf16(af[i], bfr[j], acc[i][j], 0, 0, 0);
    }
    __builtin_amdgcn_s_barrier();
    __builtin_amdgcn_sched_barrier(0);
  }

  if (EPI == 1) {
    #pragma unroll
    for (int i = 0; i < 4; ++i) {
      #pragma unroll
      for (int r = 0; r < 4; ++r) {
        int row = m0 + wr + i * 16 + q * 4 + r;
        float s = 0.f;
        #pragma unroll
        for (int j = 0; j < 4; ++j) {
          float p = __expf(acc[i][j][r] * scale);
          s += p;
          int col = n0 + wc + j * 16 + r16;
          ((u16*)C)[(long)bz * cBatch + (long)row * ldc + col] = f2bf(p);
        }
        s += __shfl_xor(s, 1); s += __shfl_xor(s, 2);
        s += __shfl_xor(s, 4); s += __shfl_xor(s, 8);
        if (r16 == 0) atomicAdd(&L[(long)bz * NPIX + lOff + row], s);
      }
    }
    return;
  }

  #pragma unroll
  for (int i = 0; i < 4; ++i) {
    #pragma unroll
    for (int r = 0; r < 4; ++r) {
      int row = m0 + wr + i * 16 + q * 4 + r;
      float inv = 1.0f;
      if (EPI == 2) inv = 1.0f / L[(long)bz * NPIX + lOff + row];
      #pragma unroll
      for (int j = 0; j < 4; ++j) {
        int col = n0 + wc + j * 16 + r16;
        float v = acc[i][j][r] * scale;
        if (EPI == 2) v *= inv;
        if (BIASMODE == 1) v += bias[row];
        if (BIASMODE == 2) v += bias[col];
        long off = (long)bz * cBatch + (long)row * ldc + col;
        if (RESID) v += resid[(long)bz * rBatch + (long)row * ldc + col];
        if (OUTF32) ((float*)C)[off] = v;
        else        ((u16*)C)[off] = f2bf(v);
      }
    }
  }
}

// ---- 256x256 NT GEMM: fine-phase schedule (T2+T3+T4+T5), exp epilogue ----
// 8 waves, BK=64, 2 dbuf. Half-tile = 128 rows x 64 cols (16KB, 2 gloads).
// Per K-tile 4 phases (mh x kk). Staging stagger (race-free by last-read
// analysis; B regs reused across mh so B(t) is free after P3, A(t) after P4):
//   P1: stage A-lo(t+1) [dbuf^1]   P2: stage A-hi(t+1) [dbuf^1]
//   P4: stage B-lo(t+2)+B-hi(t+2) [dbuf, B(t) freed after P3]
// Group end: counted vmcnt(4) (leaves the just-issued B-pair in flight;
// confirms A(t+1),B(t+1)). Never drains to 0 until the tail.
// Per phase: {ds_read quadrant; stage; barrier; lgkmcnt(0); sched_barrier;
//             setprio(1); 16 MFMA; setprio(0); barrier}.
__global__ __launch_bounds__(512, 1) void gemm256_exp(
    const u16* __restrict__ A, int lda, long aBatch,
    const u16* __restrict__ B, int ldb, long bBatch,
    u16* __restrict__ C, int ldc, long cBatch,
    float* __restrict__ Lp,
    int K, float scale) {
  __shared__ u16 SH[2][32768];  // [dbuf][A 16384 | B 16384]
  const int t = threadIdx.x;

  int nwgx = gridDim.x, nwgy = gridDim.y;
  int flat = blockIdx.x + nwgx * (blockIdx.y + nwgy * blockIdx.z);
  int nwg = nwgx * nwgy * gridDim.z;
  int newflat = (flat % 8) * (nwg / 8) + flat / 8;
  const int bx = newflat % nwgx;
  int tmpf = newflat / nwgx;
  const int by = tmpf % nwgy;
  const int bz = tmpf / nwgy;

  const int m0 = by * 256;
  const int n0 = bx * 256;
  const u16* Ab = A + (long)bz * aBatch;
  const u16* Bb = B + (long)bz * bBatch;
  u16* Cb = C + (long)bz * cBatch;

  const int lane = t & 63;
  const int wid = t >> 6;
  const int wrow = (wid >> 2) * 128;  // 0 / 128
  const int wcol = (wid & 3) * 64;    // 0 / 64 / 128 / 192
  const int r16 = lane & 15;
  const int q = lane >> 4;
  const int rsw = r16 & 7;

  const int sRow = t >> 3;                               // + i*64
  const int sCol = ((t & 7) ^ ((t >> 3) & 7)) * 8;       // u16

  // stage one 16KB half-tile (2 gloads): half h covers rows h*128..h*128+127
  auto stageA = [&](int d, int k0, int h) {
    u16* base = &SH[d][0];
    #pragma unroll
    for (int i = h * 2; i < h * 2 + 2; ++i)
      __builtin_amdgcn_global_load_lds(
          (const __attribute__((address_space(1))) unsigned int*)(Ab + (long)(m0 + i * 64 + sRow) * lda + k0 + sCol),
          (__attribute__((address_space(3))) unsigned int*)(base + i * 4096 + wid * 512),
          16, 0, 0);
  };
  auto stageB = [&](int d, int k0, int h) {
    u16* base = &SH[d][16384];
    #pragma unroll
    for (int i = h * 2; i < h * 2 + 2; ++i)
      __builtin_amdgcn_global_load_lds(
          (const __attribute__((address_space(1))) unsigned int*)(Bb + (long)(n0 + i * 64 + sRow) * ldb + k0 + sCol),
          (__attribute__((address_space(3))) unsigned int*)(base + i * 4096 + wid * 512),
          16, 0, 0);
  };

  f32x4 acc[8][4] = {};
  const int nt = K / 64;   // 8 for K=512

  // prologue: tile0 fully + B(1); leave B(1) in flight
  stageA(0, 0, 0); stageA(0, 0, 1);
  stageB(0, 0, 0); stageB(0, 0, 1);
  stageB(1, 64, 0); stageB(1, 64, 1);
  asm volatile("s_waitcnt vmcnt(4)" ::: "memory");
  __builtin_amdgcn_s_barrier();
  __builtin_amdgcn_sched_barrier(0);

  for (int tt = 0; tt < nt; ++tt) {
    const int d = tt & 1;
    const u16* As_ = &SH[d][0];
    const u16* Bs_ = As_ + 16384;
    const int cs0 = (q ^ rsw) * 8;        // kk0 swizzled u16 col
    const int cs1 = ((4 + q) ^ rsw) * 8;  // kk1

    bf16x8 a[4], b0[4], b1[4];

    // ---- P1: (mh0, kk0); stage A-lo(t+1)
    #pragma unroll
    for (int i = 0; i < 4; ++i)
      a[i] = *(const bf16x8*)&As_[(wrow + i * 16 + r16) * 64 + cs0];
    #pragma unroll
    for (int i = 0; i < 4; ++i)
      b0[i] = *(const bf16x8*)&Bs_[(wcol + i * 16 + r16) * 64 + cs0];
    if (tt + 1 < nt) stageA(d ^ 1, (tt + 1) * 64, 0);
    __builtin_amdgcn_s_barrier();
    asm volatile("s_waitcnt lgkmcnt(0)" ::: "memory");
    __builtin_amdgcn_sched_barrier(0);
    __builtin_amdgcn_s_setprio(1);
    #pragma unroll
    for (int mi = 0; mi < 4; ++mi)
      #pragma unroll
      for (int ni = 0; ni < 4; ++ni)
        acc[mi][ni] = __builtin_amdgcn_mfma_f32_16x16x32_bf16(a[mi], b0[ni], acc[mi][ni], 0, 0, 0);
    __builtin_amdgcn_s_setprio(0);
    __builtin_amdgcn_s_barrier();

    // ---- P2: (mh1, kk0); stage A-hi(t+1)
    #pragma unroll
    for (int i = 0; i < 4; ++i)
      a[i] = *(const bf16x8*)&As_[(wrow + (4 + i) * 16 + r16) * 64 + cs0];
    if (tt + 1 < nt) stageA(d ^ 1, (tt + 1) * 64, 1);
    __builtin_amdgcn_s_barrier();
    asm volatile("s_waitcnt lgkmcnt(0)" ::: "memory");
    __builtin_amdgcn_sched_barrier(0);
    __builtin_amdgcn_s_setprio(1);
    #pragma unroll
    for (int mi = 0; mi < 4; ++mi)
      #pragma unroll
      for (int ni = 0; ni < 4; ++ni)
        acc[4 + mi][ni] = __builtin_amdgcn_mfma_f32_16x16x32_bf16(a[mi], b0[ni], acc[4 + mi][ni], 0, 0, 0);
    __builtin_amdgcn_s_setprio(0);
    __builtin_amdgcn_s_barrier();

    // ---- P3: (mh0, kk1); no stage
    #pragma unroll
    for (int i = 0; i < 4; ++i)
      a[i] = *(const bf16x8*)&As_[(wrow + i * 16 + r16) * 64 + cs1];
    #pragma unroll
    for (int i = 0; i < 4; ++i)
      b1[i] = *(const bf16x8*)&Bs_[(wcol + i * 16 + r16) * 64 + cs1];
    __builtin_amdgcn_s_barrier();
    asm volatile("s_waitcnt lgkmcnt(0)" ::: "memory");
    __builtin_amdgcn_sched_barrier(0);
    __builtin_amdgcn_s_setprio(1);
    #pragma unroll
    for (int mi = 0; mi < 4; ++mi)
      #pragma unroll
      for (int ni = 0; ni < 4; ++ni)
        acc[mi][ni] = __builtin_amdgcn_mfma_f32_16x16x32_bf16(a[mi], b1[ni], acc[mi][ni], 0, 0, 0);
    __builtin_amdgcn_s_setprio(0);
    __builtin_amdgcn_s_barrier();

    // ---- P4: (mh1, kk1); stage B(t+2) both halves (B(t) freed after P3)
    #pragma unroll
    for (int i = 0; i < 4; ++i)
      a[i] = *(const bf16x8*)&As_[(wrow + (4 + i) * 16 + r16) * 64 + cs1];
    if (tt + 2 < nt) { stageB(d, (tt + 2) * 64, 0); stageB(d, (tt + 2) * 64, 1); }
    __builtin_amdgcn_s_barrier();
    asm volatile("s_waitcnt lgkmcnt(0)" ::: "memory");
    __builtin_amdgcn_sched_barrier(0);
    __builtin_amdgcn_s_setprio(1);
    #pragma unroll
    for (int mi = 0; mi < 4; ++mi)
      #pragma unroll
      for (int ni = 0; ni < 4; ++ni)
        acc[4 + mi][ni] = __builtin_amdgcn_mfma_f32_16x16x32_bf16(a[mi], b1[ni], acc[4 + mi][ni], 0, 0, 0);
    __builtin_amdgcn_s_setprio(0);
    // group end: counted wait (confirm A(t+1),B(t+1); leave B(t+2) in flight)
    if (tt + 2 < nt) {
      asm volatile("s_waitcnt vmcnt(4)" ::: "memory");
    } else {
      asm volatile("s_waitcnt vmcnt(0)" ::: "memory");
    }
    __builtin_amdgcn_s_barrier();
    __builtin_amdgcn_sched_barrier(0);
  }

  // ---- epilogue: exp, direct bf16 stores, LDS partial rowsums (no atomics)
  float* Lsh = (float*)&SH[0][0];  // [2][128][4] f32 = 4KB overlay
  #pragma unroll
  for (int mi = 0; mi < 8; ++mi) {
    #pragma unroll
    for (int r = 0; r < 4; ++r) {
      int lrow = mi * 16 + q * 4 + r;           // 0..127 within wave half
      int row = m0 + wrow + lrow;
      float s = 0.f;
      #pragma unroll
      for (int ni = 0; ni < 4; ++ni) {
        float p = __expf(acc[mi][ni][r] * scale);
        s += p;
        Cb[(long)row * ldc + n0 + wcol + ni * 16 + r16] = f2bf(p);
      }
      s += __shfl_xor(s, 1); s += __shfl_xor(s, 2);
      s += __shfl_xor(s, 4); s += __shfl_xor(s, 8);
      if (r16 == 0) Lsh[((wrow >> 7) * 128 + lrow) * 4 + (wcol >> 6)] = s;
    }
  }
  __syncthreads();
  if (t < 256) {
    const float* lr = &Lsh[t * 4];
    Lp[((long)bz * 16 + bx) * NPIX + m0 + t] = lr[0] + lr[1] + lr[2] + lr[3];
  }
}

extern "C" void kernel_launch(void* const* d_in, const int* in_sizes, int n_in,
                              void* d_out, int out_size, void* d_ws, size_t ws_size,
                              hipStream_t stream) {
  const float* x   = (const float*)d_in[0];
  const float* gnw = (const float*)d_in[1];
  const float* gnb = (const float*)d_in[2];
  const float* wq  = (const float*)d_in[3];
  const float* bq  = (const float*)d_in[4];
  const float* wk  = (const float*)d_in[5];
  const float* bk_ = (const float*)d_in[6];
  const float* wv  = (const float*)d_in[7];
  const float* bv  = (const float*)d_in[8];
  const float* wo  = (const float*)d_in[9];
  const float* bo  = (const float*)d_in[10];
  float* out = (float*)d_out;

  char* wsp = (char*)d_ws;
  auto alloc = [&](size_t bytes) {
    char* r = wsp; wsp += (bytes + 255) & ~(size_t)255; return r;
  };
  u16* wqb = (u16*)alloc((size_t)CC * CC * 2);
  u16* wkb = (u16*)alloc((size_t)CC * CC * 2);
  u16* wvb = (u16*)alloc((size_t)CC * CC * 2);
  u16* wob = (u16*)alloc((size_t)CC * CC * 2);
  float* bqk = (float*)alloc((size_t)2 * CC * 4);
  float* gpart = (float*)alloc((size_t)NB * NG * 8 * 2 * 4);
  float* stats = (float*)alloc((size_t)NB * NG * 2 * 4);
  float* lsum = (float*)alloc((size_t)NB * NPIX * 4);
  float* lpart = (float*)alloc((size_t)NB * 16 * NPIX * 4);
  u16* hn  = (u16*)alloc((size_t)NB * NPIX * CC * 2);
  u16* qkt = (u16*)alloc((size_t)NB * NPIX * (2 * CC) * 2);  // [B][N][1024] = q|k
  u16* vcn = (u16*)alloc((size_t)NB * CC * NPIX * 2);
  u16* ot  = (u16*)alloc((size_t)NB * NPIX * CC * 2);
  size_t used = (size_t)(wsp - (char*)d_ws);
  size_t rem = ws_size > used ? ws_size - used : 0;
  int CH = 256;
  if ((size_t)NB * 1024 * NPIX * 2 <= rem) CH = 1024;
  if ((size_t)NB * 4096 * NPIX * 2 <= rem) CH = 4096;
  u16* SP = (u16*)alloc((size_t)NB * CH * NPIX * 2);

  dim3 blk(256);
  f2bf4x4_kernel<<<dim3(CC * CC / 1024, 4), blk, 0, stream>>>(
      wq, wk, wv, wo, wqb, wkb, wvb, wob);
  concat2_kernel<<<2 * CC / 256, blk, 0, stream>>>(bq, bk_, bqk);
  hipMemsetAsync(lsum, 0, (size_t)NB * NPIX * 4, stream);

  gn_stats_part<<<NB * NG * 8, blk, 0, stream>>>(x, gpart);
  gn_stats_fin<<<1, 64, 0, stream>>>(gpart, stats);
  gn_apply_kernel<<<dim3(NPIX / 64, CC / 64, NB), blk, 0, stream>>>(x, stats, gnw, gnb, hn);

  // Fused QK: qk_t[n, o] = sum_c hn[n,c]*wqk[o,c] + bqk[o], o in [0,1024)
  gemm_nt<0, 2, 0, 0><<<dim3(2 * CC / BN, NPIX / BM, NB), blk, 0, stream>>>(
      hn, CC, (long)NPIX * CC, wqb, CC, 0, qkt, 2 * CC, (long)NPIX * 2 * CC,
      bqk, nullptr, 0, nullptr, 0, CC, 1.0f);
  // V: v_cn[c,n] = sum_ch wv[c,ch]*hn[n,ch] + bv[c]  (M=CC, N=NPIX)
  gemm_nt<0, 1, 0, 0><<<dim3(NPIX / BN, CC / BM, NB), blk, 0, stream>>>(
      wvb, CC, 0, hn, CC, (long)NPIX * CC, vcn, NPIX, (long)CC * NPIX,
      bv, nullptr, 0, nullptr, 0, CC, 1.0f);

  const u16* qt = qkt;
  const u16* kt = qkt + CC;
  const float scale = 0.044194173824159216f;  // 512^-0.5
  for (int i0 = 0; i0 < NPIX; i0 += CH) {
    // P[i,j] = exp(scale * sum_c q[i,c]*k[j,c]); rowsums -> lpart -> lsum
    if (CH == 4096) {
      gemm256_exp<<<dim3(NPIX / 256, NPIX / 256, NB), dim3(512), 0, stream>>>(
          qt, 2 * CC, (long)NPIX * 2 * CC, kt, 2 * CC, (long)NPIX * 2 * CC,
          SP, NPIX, (long)CH * NPIX, lpart, CC, scale);
      lred_kernel<<<NB * NPIX / 256, blk, 0, stream>>>(lpart, lsum);
    } else {
      gemm_nt<0, 0, 0, 1><<<dim3(NPIX / BN, CH / BM, NB), blk, 0, stream>>>(
          qt + (long)i0 * 2 * CC, 2 * CC, (long)NPIX * 2 * CC, kt, 2 * CC, (long)NPIX * 2 * CC,
          SP, NPIX, (long)CH * NPIX, nullptr, nullptr, 0, lsum, i0, CC, scale);
    }
    // O_t[i,c] = (sum_j P[i,j]*v_cn[c,j]) / L[i]
    gemm_nt<0, 0, 0, 2><<<dim3(CC / BN, CH / BM, NB), blk, 0, stream>>>(
        SP, NPIX, (long)CH * NPIX, vcn, NPIX, (long)CC * NPIX,
        ot + (long)i0 * CC, CC, (long)NPIX * CC, nullptr, nullptr, 0, lsum, i0, NPIX, 1.0f);
  }

  // out[o,n] = sum_c wo[o,c]*ot[n,c] + bo[o] + x[o,n]  (M=CC, N=NPIX), f32 out
  gemm_nt<1, 1, 1, 0><<<dim3(NPIX / BN, CC / BM, NB), blk, 0, stream>>>(
      wob, CC, 0, ot, CC, (long)NPIX * CC, out, NPIX, (long)CC * NPIX,
      bo, x, (long)CC * NPIX, nullptr, 0, CC, 1.0f);
}